// Round 6
// baseline (117.038 us; speedup 1.0000x reference)
//
#include <hip/hip_runtime.h>
#include <hip/hip_bf16.h>

#define NFEAT 256
#define NATOMS 4096
#define NCLAUSES 512
#define ROWS 8
#define XPAD 12          // floats per feature column: uniform LDS bank spread (gcd(12,32)=4)
#define BLOCK 256

// hardware transcendentals: v_exp_f32 computes 2^x
#define EXP2F(v) __builtin_amdgcn_exp2f(v)
#define RCPF(v)  __builtin_amdgcn_rcpf(v)

// Pre-kernel:
//  blocks 0..15 : pack per-atom constants abf[a] = {A, B, asfloat(fid*XPAD), 0}
//                 where e = exp(-z) = exp2(A*x + B)
//  block 16     : CSR seg via LDS binary search; rank clauses by length;
//                 pair rank-k with rank-(511-k) so each thread's total work is
//                 ~uniform AND wave-adjacent lanes get near-equal lengths
//                 (consecutive ranks) -> wave trip ~= lane mean, ~89% lane eff.
//                 slot[2k]   = {sA, eA, sB, eB} (as-int floats)
//                 slot[2k+1] = {gA, gB, 0, 0},  g = gate*leaf
__global__ void cln_pre(const float* __restrict__ w, const float* __restrict__ eta,
                        const float* __restrict__ leaf, const float* __restrict__ gate,
                        const int* __restrict__ fid, const int* __restrict__ sgn,
                        const int* __restrict__ cid,
                        float4* __restrict__ abf, float4* __restrict__ slot) {
    __shared__ int lcid[NATOMS];            // 16 KB
    __shared__ int lseg[NCLAUSES + 1];
    __shared__ __align__(16) int llen[NCLAUSES];
    __shared__ int lperm[NCLAUSES];
    const int tid = threadIdx.x;
    const int bid = blockIdx.x;
    const float K = 144.269504088896340736f;  // B_CONST * log2(e), B=100

    if (bid < NATOMS / BLOCK) {             // packers
        const int i = bid * BLOCK + tid;
        const float s = (sgn[i] == 0) ? -1.f : 1.f;
        const float a2 = -s * K * w[i];
        const float b2 =  s * K * (eta[i] - 0.01f);
        abf[i] = make_float4(a2, b2, __int_as_float(fid[i] * XPAD), 0.f);
        return;
    }

    // ---- block 16: pairing ----
    for (int k = tid; k < NATOMS; k += BLOCK) lcid[k] = cid[k];
    __syncthreads();
    for (int k = tid; k <= NCLAUSES; k += BLOCK) {   // lower_bound in LDS
        int lo = 0, hi = NATOMS;
        while (lo < hi) { int mid = (lo + hi) >> 1; if (lcid[mid] < k) lo = mid + 1; else hi = mid; }
        lseg[k] = lo;
    }
    __syncthreads();
    for (int c = tid; c < NCLAUSES; c += BLOCK) llen[c] = lseg[c + 1] - lseg[c];
    __syncthreads();
    for (int c = tid; c < NCLAUSES; c += BLOCK) {    // stable rank by length
        const int L = llen[c];
        int r = 0;
        const int4* l4 = (const int4*)llen;
        for (int j4 = 0; j4 < NCLAUSES / 4; ++j4) {
            const int4 v = l4[j4];
            const int j = j4 * 4;
            r += (v.x < L) || (v.x == L && (j + 0) < c);
            r += (v.y < L) || (v.y == L && (j + 1) < c);
            r += (v.z < L) || (v.z == L && (j + 2) < c);
            r += (v.w < L) || (v.w == L && (j + 3) < c);
        }
        lperm[r] = c;
    }
    __syncthreads();
    if (tid < NCLAUSES / 2) {
        const int cA = lperm[tid];
        const int cB = lperm[NCLAUSES - 1 - tid];
        slot[2 * tid]     = make_float4(__int_as_float(lseg[cA]), __int_as_float(lseg[cA + 1]),
                                        __int_as_float(lseg[cB]), __int_as_float(lseg[cB + 1]));
        slot[2 * tid + 1] = make_float4(gate[cA] * leaf[cA], gate[cB] * leaf[cB], 0.f, 0.f);
    }
}

__global__ __launch_bounds__(BLOCK, 4) void cln_main(
        const float* __restrict__ x, const float4* __restrict__ abf,
        const float4* __restrict__ slot, float* __restrict__ y) {
    __shared__ __align__(16) float xT[NFEAT * XPAD];   // 12 KB; reused for reduce

    const int tid = threadIdx.x;
    const int row0 = blockIdx.x * ROWS;

    // Stage 8 rows of x, transposed: xT[fid*XPAD + r]. Coalesced.
#pragma unroll
    for (int k = 0; k < ROWS; ++k)
        xT[tid * XPAD + k] = x[(row0 + k) * NFEAT + tid];
    __syncthreads();

    const float4 sl0 = slot[2 * tid];
    const float4 sl1 = slot[2 * tid + 1];
    const int seg4[4] = {__float_as_int(sl0.x), __float_as_int(sl0.y),
                         __float_as_int(sl0.z), __float_as_int(sl0.w)};
    const float g2[2] = {sl1.x, sl1.y};

    float acc[ROWS];
#pragma unroll
    for (int r = 0; r < ROWS; ++r) acc[r] = 0.f;

    // Two balanced clauses per thread, each a clean loop (no mid-loop flush).
    // p >= 1 always; clamp 1e37 prevents fmaf(inf,0,inf)=NaN; clamped clause
    // -> rcp ~ 1e-37 ~ 0 which matches the reference's underflow.
#pragma unroll
    for (int half = 0; half < 2; ++half) {
        const int s = seg4[2 * half];
        const int e = seg4[2 * half + 1];
        const int elast = e - 1;
        float p[ROWS];
#pragma unroll
        for (int r = 0; r < ROWS; ++r) p[r] = 1.f;

        // prefetch depth 2: break the per-iteration global-load dependency
        const int i0 = min(s, NATOMS - 1);
        float4 t0 = abf[i0];
        float4 t1 = abf[min(i0 + 1, NATOMS - 1)];
        for (int a = s; a < e; ++a) {
            const float4 tn = abf[min(a + 2, elast)];
            const int xo = __float_as_int(t0.z);
            const float4 xa = *(const float4*)(xT + xo);
            const float4 xb = *(const float4*)(xT + xo + 4);
            const float xv[ROWS] = {xa.x, xa.y, xa.z, xa.w, xb.x, xb.y, xb.z, xb.w};
#pragma unroll
            for (int r = 0; r < ROWS; ++r) {
                const float ev = EXP2F(fmaf(t0.x, xv[r], t0.y));
                p[r] = fminf(fmaf(p[r], ev, p[r]), 1e37f);   // p *= (1 + e)
            }
            t0 = t1; t1 = tn;
        }
        const float g = g2[half];
#pragma unroll
        for (int r = 0; r < ROWS; ++r)
            acc[r] = fmaf(g, RCPF(p[r]), acc[r]);   // empty clause: rcp(1)=1 -> +g
    }

    // Block reduction: wave shuffle-reduce each row, 4 wave-partials via LDS.
    __syncthreads();                 // xT no longer needed as x-tile
    float* red = xT;
    const int wave = tid >> 6;
    const int lane = tid & 63;
#pragma unroll
    for (int r = 0; r < ROWS; ++r) {
        float v = acc[r];
#pragma unroll
        for (int off = 32; off > 0; off >>= 1)
            v += __shfl_down(v, off, 64);
        if (lane == 0) red[wave * ROWS + r] = v;
    }
    __syncthreads();
    if (tid < ROWS) {
        float sres = 0.f;
#pragma unroll
        for (int wv = 0; wv < BLOCK / 64; ++wv)
            sres += red[wv * ROWS + tid];
        y[row0 + tid] = sres;
    }
}

extern "C" void kernel_launch(void* const* d_in, const int* in_sizes, int n_in,
                              void* d_out, int out_size, void* d_ws, size_t ws_size,
                              hipStream_t stream) {
    const float* x    = (const float*)d_in[0];
    const float* w    = (const float*)d_in[1];
    const float* eta  = (const float*)d_in[2];
    const float* leaf = (const float*)d_in[3];
    const float* gate = (const float*)d_in[4];
    const int*   fid  = (const int*)d_in[5];
    const int*   sgn  = (const int*)d_in[6];
    const int*   cid  = (const int*)d_in[7];
    float* y = (float*)d_out;

    char* ws = (char*)d_ws;
    float4* abf  = (float4*)ws;                                  // 64 KB
    float4* slot = (float4*)(ws + NATOMS * sizeof(float4));      // 8 KB

    const int bsz = in_sizes[0] / NFEAT;  // 8192

    cln_pre<<<NATOMS / BLOCK + 1, BLOCK, 0, stream>>>(w, eta, leaf, gate, fid, sgn, cid,
                                                      abf, slot);
    cln_main<<<bsz / ROWS, BLOCK, 0, stream>>>(x, abf, slot, y);
}

// Round 7
// 116.378 us; speedup vs baseline: 1.0057x; 1.0057x over previous
//
#include <hip/hip_runtime.h>
#include <hip/hip_bf16.h>

#define NFEAT 256
#define NATOMS 4096
#define NCLAUSES 512
#define TROWS 64         // batch rows per block tile (= lanes per wave)
#define NSPLIT 4         // clause splits; grid = 128 tiles x 4 = 512 blocks = 2/CU
#define BLOCK 256

// hardware transcendentals: v_exp_f32 computes 2^x
#define EXP2F(v) __builtin_amdgcn_exp2f(v)
#define RCPF(v)  __builtin_amdgcn_rcpf(v)
#define RFL(v)   __builtin_amdgcn_readfirstlane(v)

// Precompute per-atom record abf[a] = {A, B, asfloat(fid), 0}:
//   e = exp(-z) = exp2(A*x + B);  A = -s*B_CONST*log2e*w ; B = s*B_CONST*log2e*(eta-eps)
// CSR seg[0..512] by binary search over sorted clause_ids; gl[c] = gate*leaf.
__global__ void cln_pre(const float* __restrict__ w, const float* __restrict__ eta,
                        const float* __restrict__ leaf, const float* __restrict__ gate,
                        const int* __restrict__ fid, const int* __restrict__ sgn,
                        const int* __restrict__ cid,
                        float4* __restrict__ abf, int* __restrict__ seg,
                        float* __restrict__ gl) {
    int i = blockIdx.x * blockDim.x + threadIdx.x;
    const float K = 144.269504088896340736f;  // B_CONST * log2(e), B=100
    if (i < NATOMS) {
        float s = (sgn[i] == 0) ? -1.f : 1.f;
        float a2 = -s * K * w[i];
        float b2 =  s * K * (eta[i] - 0.01f);
        abf[i] = make_float4(a2, b2, __int_as_float(fid[i]), 0.f);
    }
    if (i <= NCLAUSES) {
        int lo = 0, hi = NATOMS;
        while (lo < hi) { int mid = (lo + hi) >> 1; if (cid[mid] < i) lo = mid + 1; else hi = mid; }
        seg[i] = lo;
    }
    if (i < NCLAUSES) gl[i] = gate[i] * leaf[i];
}

// lane = batch row; wave walks its 32 clauses' atoms UNIFORMLY:
//  - abf[a] wave-uniform -> 1 cache line / load (kills the R4-R6 L1 divergence)
//  - x via LDS xT[f*64 + (r+f)&63]: staging writes conflict-free, reads 2-way (free)
//  - clause boundaries are wave-uniform branches (no divergence, no balancing needed)
__global__ __launch_bounds__(BLOCK, 2) void cln_main(
        const float* __restrict__ x, const float4* __restrict__ abf,
        const int* __restrict__ seg, const float* __restrict__ gl,
        float* __restrict__ y) {
    __shared__ float xT[NFEAT * TROWS];   // exactly 64 KB

    const int tid  = threadIdx.x;
    const int wave = tid >> 6;
    const int lane = tid & 63;
    const int tile  = blockIdx.x >> 2;    // 4 consecutive blocks share a tile (L3 reuse)
    const int split = blockIdx.x & 3;
    const int row0  = tile * TROWS;

    // Stage 64 rows x 256 feats, rotate-swizzled. Each wave stages 16 rows.
    // Global: lanes read 64 consecutive floats of one row (coalesced 256B).
    // LDS write bank = (r + f) & 31 with f = fb*64+lane -> (r+lane)%32: 2 lanes/bank, free.
#pragma unroll
    for (int k = 0; k < 16; ++k) {
        const int r = wave * 16 + k;
#pragma unroll
        for (int fb = 0; fb < 4; ++fb) {
            const int f = fb * 64 + lane;
            xT[f * TROWS + ((r + f) & 63)] = x[(row0 + r) * NFEAT + f];
        }
    }
    __syncthreads();

    // This wave's clause range: 32 clauses.
    const int c0 = split * (NCLAUSES / NSPLIT) + wave * (NCLAUSES / NSPLIT / 4);
    float acc = 0.f;

    for (int c = c0; c < c0 + 32; ++c) {
        const int s = RFL(seg[c]);
        const int e = RFL(seg[c + 1]);
        const float g = gl[c];
        float p = 1.f;
        for (int a = s; a < e; ++a) {
            const float4 t = abf[a];                   // wave-uniform address
            const int rot = RFL(__float_as_int(t.z));  // fid, scalar
            const float xv = xT[(rot << 6) + ((lane + rot) & 63)];
            const float ev = EXP2F(fmaf(t.x, xv, t.y));
            // p *= (1+e); clamp: p=inf then ev=0 would give fmaf(inf,0,inf)=NaN.
            p = fminf(fmaf(p, ev, p), 1e37f);
        }
        acc = fmaf(g, RCPF(p), acc);   // empty clause: rcp(1)=1 -> +g (matches exp(0))
    }

    // Partial sum for this lane's row; <=16 adds per address across the grid.
    atomicAdd(&y[row0 + lane], acc);
}

extern "C" void kernel_launch(void* const* d_in, const int* in_sizes, int n_in,
                              void* d_out, int out_size, void* d_ws, size_t ws_size,
                              hipStream_t stream) {
    const float* x    = (const float*)d_in[0];
    const float* w    = (const float*)d_in[1];
    const float* eta  = (const float*)d_in[2];
    const float* leaf = (const float*)d_in[3];
    const float* gate = (const float*)d_in[4];
    const int*   fid  = (const int*)d_in[5];
    const int*   sgn  = (const int*)d_in[6];
    const int*   cid  = (const int*)d_in[7];
    float* y = (float*)d_out;

    char* ws = (char*)d_ws;
    float4* abf = (float4*)ws;                                   // 64 KB
    int*    seg = (int*)(ws + NATOMS * sizeof(float4));          // 2052 B
    float*  gl  = (float*)(ws + NATOMS * sizeof(float4) + (NCLAUSES + 1 + 3) * sizeof(int)); // 2 KB

    const int bsz = in_sizes[0] / NFEAT;  // 8192

    hipMemsetAsync(d_out, 0, bsz * sizeof(float), stream);   // zero for atomicAdd
    cln_pre<<<NATOMS / BLOCK, BLOCK, 0, stream>>>(w, eta, leaf, gate, fid, sgn, cid,
                                                  abf, seg, gl);
    cln_main<<<(bsz / TROWS) * NSPLIT, BLOCK, 0, stream>>>(x, abf, seg, gl, y);
}

// Round 8
// 101.280 us; speedup vs baseline: 1.1556x; 1.1491x over previous
//
#include <hip/hip_runtime.h>
#include <hip/hip_bf16.h>

#define NFEAT 256
#define NATOMS 4096
#define NCLAUSES 512
#define TROWS 64         // batch rows per tile (= lanes per wave)
#define NSPLIT 4         // grid = 128 tiles x 4 = 512 blocks of 512 = 2 blocks/CU
#define BLOCK 512        // 8 waves -> 4 waves/SIMD (2 blocks/CU), 2x R7's TLP

// hardware transcendentals: v_exp_f32 computes 2^x
#define EXP2F(v) __builtin_amdgcn_exp2f(v)
#define RCPF(v)  __builtin_amdgcn_rcpf(v)
#define RFL(v)   __builtin_amdgcn_readfirstlane(v)

// Pre-kernel.
// blocks 0..15: pack per-atom record abf[i] = {A, B, asfloat(fid | last<<8), g}
//   e = exp(-z) = exp2(A*x + B); A = -s*B*log2e*w; B = s*B*log2e*(eta-eps)
//   last = atom is final atom of its clause (stream is sorted by clause);
//   g = gate*leaf of that clause if last, else 0. This moves clause
//   boundaries INTO the contiguous atom stream -> main can prefetch across
//   boundaries and flush on a wave-uniform flag.
// block 16: CSR seg[0..512]; esum[32] = per wave-slot (16 clauses each) sum
//   of gate*leaf over EMPTY clauses (they contribute exp(0)=1 per row).
__global__ void cln_pre(const float* __restrict__ w, const float* __restrict__ eta,
                        const float* __restrict__ leaf, const float* __restrict__ gate,
                        const int* __restrict__ fid, const int* __restrict__ sgn,
                        const int* __restrict__ cid,
                        float4* __restrict__ abf, int* __restrict__ seg,
                        float* __restrict__ esum) {
    __shared__ int lcid[NATOMS];            // 16 KB (block 16 only)
    __shared__ int lseg[NCLAUSES + 1];
    __shared__ float lesum[32];
    const int tid = threadIdx.x;
    const int bid = blockIdx.x;
    const float K = 144.269504088896340736f;  // B_CONST * log2(e), B=100

    if (bid < NATOMS / 256) {               // packers
        const int i = bid * 256 + tid;
        const float s = (sgn[i] == 0) ? -1.f : 1.f;
        const float a2 = -s * K * w[i];
        const float b2 =  s * K * (eta[i] - 0.01f);
        const int c = cid[i];
        const bool last = (i == NATOMS - 1) || (cid[i + 1] != c);
        const int z = fid[i] | (last ? 256 : 0);
        const float g = last ? gate[c] * leaf[c] : 0.f;
        abf[i] = make_float4(a2, b2, __int_as_float(z), g);
        return;
    }

    // ---- block 16 ----
    for (int k = tid; k < NATOMS; k += 256) lcid[k] = cid[k];
    if (tid < 32) lesum[tid] = 0.f;
    __syncthreads();
    for (int k = tid; k <= NCLAUSES; k += 256) {   // lower_bound in LDS
        int lo = 0, hi = NATOMS;
        while (lo < hi) { int mid = (lo + hi) >> 1; if (lcid[mid] < k) lo = mid + 1; else hi = mid; }
        lseg[k] = lo;
    }
    __syncthreads();
    for (int c = tid; c < NCLAUSES; c += 256)
        if (lseg[c + 1] == lseg[c])
            atomicAdd(&lesum[c >> 4], gate[c] * leaf[c]);
    __syncthreads();
    for (int k = tid; k <= NCLAUSES; k += 256) seg[k] = lseg[k];
    if (tid < 32) esum[tid] = lesum[tid];
}

// lane = batch row; wave walks its 16 clauses' CONTIGUOUS atom range with
// chunk-4 double-buffered register prefetch. All control flow wave-uniform.
__global__ __launch_bounds__(BLOCK, 4) void cln_main(
        const float* __restrict__ x, const float4* __restrict__ abf,
        const int* __restrict__ seg, const float* __restrict__ esum,
        float* __restrict__ y) {
    __shared__ float xT[NFEAT * TROWS];   // 64 KB, rotate-swizzled

    const int tid  = threadIdx.x;
    const int wave = tid >> 6;
    const int lane = tid & 63;
    const int tile  = blockIdx.x >> 2;
    const int split = blockIdx.x & 3;
    const int row0  = tile * TROWS;

    // Stage 64 rows x 256 feats. Each of 8 waves stages 8 rows; coalesced
    // 256B global reads; LDS bank = (r+lane)&31 -> conflict-free.
#pragma unroll
    for (int k = 0; k < 8; ++k) {
        const int r = wave * 8 + k;
#pragma unroll
        for (int fb = 0; fb < 4; ++fb) {
            const int f = fb * 64 + lane;
            xT[f * TROWS + ((r + f) & 63)] = x[(row0 + r) * NFEAT + f];
        }
    }
    __syncthreads();

    const int slot = split * 8 + wave;            // 32 slots of 16 clauses
    const int c0 = slot * 16;
    const int s = seg[c0];
    const int e = seg[c0 + 16];

    float acc = esum[slot];    // empty clauses' contribution (wave-uniform)
    float p = 1.f;

    float4 b0[4], b1[4];
#pragma unroll
    for (int j = 0; j < 4; ++j) b0[j] = abf[min(s + j, NATOMS - 1)];

    for (int base = s; base < e; base += 4) {
#pragma unroll
        for (int j = 0; j < 4; ++j) b1[j] = abf[min(base + 4 + j, NATOMS - 1)];
        const int m = e - base;                   // wave-uniform
        int zi[4];
        float xv[4];
#pragma unroll
        for (int j = 0; j < 4; ++j) {             // issue all LDS reads up front
            zi[j] = RFL(__float_as_int(b0[j].z));
            const int f = zi[j] & 0xFF;
            xv[j] = xT[(f << 6) + ((lane + f) & 63)];
        }
#pragma unroll
        for (int j = 0; j < 4; ++j) {
            if (j < m) {
                const float ev = EXP2F(fmaf(b0[j].x, xv[j], b0[j].y));
                // p *= (1+e); clamp: p=inf then ev=0 gives fmaf(inf,0,inf)=NaN.
                p = fminf(fmaf(p, ev, p), 1e37f);
                if (zi[j] >> 8) {                 // wave-uniform clause end
                    acc = fmaf(b0[j].w, RCPF(p), acc);
                    p = 1.f;
                }
            }
        }
#pragma unroll
        for (int j = 0; j < 4; ++j) b0[j] = b1[j];
    }

    atomicAdd(&y[row0 + lane], acc);   // 32 partials per row across the grid
}

extern "C" void kernel_launch(void* const* d_in, const int* in_sizes, int n_in,
                              void* d_out, int out_size, void* d_ws, size_t ws_size,
                              hipStream_t stream) {
    const float* x    = (const float*)d_in[0];
    const float* w    = (const float*)d_in[1];
    const float* eta  = (const float*)d_in[2];
    const float* leaf = (const float*)d_in[3];
    const float* gate = (const float*)d_in[4];
    const int*   fid  = (const int*)d_in[5];
    const int*   sgn  = (const int*)d_in[6];
    const int*   cid  = (const int*)d_in[7];
    float* y = (float*)d_out;

    char* ws = (char*)d_ws;
    float4* abf  = (float4*)ws;                                      // 64 KB
    int*    seg  = (int*)(ws + NATOMS * sizeof(float4));             // 2052 B
    float*  esum = (float*)(ws + NATOMS * sizeof(float4) + 2080);    // 128 B

    const int bsz = in_sizes[0] / NFEAT;  // 8192

    hipMemsetAsync(d_out, 0, bsz * sizeof(float), stream);   // zero for atomicAdd
    cln_pre<<<NATOMS / 256 + 1, 256, 0, stream>>>(w, eta, leaf, gate, fid, sgn, cid,
                                                  abf, seg, esum);
    cln_main<<<(bsz / TROWS) * NSPLIT, BLOCK, 0, stream>>>(x, abf, seg, esum, y);
}